// Round 6
// baseline (24.385 us; speedup 1.0000x reference)
//
#include <hip/hip_runtime.h>
#include <hip/hip_bf16.h>

#define DIM 1024
#define NBLK 1024           // 4 blocks/CU x 256 CUs -> exact co-residency (spin-safe)
#define NSCORE 512          // consumer blocks: 512 x 256 = 131072 outputs
#define MAGIC 0x5A17C0DEu   // != 0xAAAAAAAA poison, != 0
#define NQ 2049             // 2048 per-row q partials + 1 bias partial

// Agent-scope relaxed atomics (sc1): write-through to the coherent point /
// cache-bypassing loads. No dirty L2 lines for cross-block data => no
// threadfence (no buffer_wbl2/inv L2 tag-walks) anywhere. Proven in R4.
__device__ __forceinline__ void st_ag(float* p, float v) {
    __hip_atomic_store(p, v, __ATOMIC_RELAXED, __HIP_MEMORY_SCOPE_AGENT);
}
__device__ __forceinline__ float ld_ag(const float* p) {
    return __hip_atomic_load(p, __ATOMIC_RELAXED, __HIP_MEMORY_SCOPE_AGENT);
}
__device__ __forceinline__ void st_agu(unsigned* p, unsigned v) {
    __hip_atomic_store(p, v, __ATOMIC_RELAXED, __HIP_MEMORY_SCOPE_AGENT);
}
__device__ __forceinline__ unsigned ld_agu(const unsigned* p) {
    return __hip_atomic_load(p, __ATOMIC_RELAXED, __HIP_MEMORY_SCOPE_AGENT);
}

// ws: flags[NBLK] @0 | qpart[NQ] @4096B | escore[n_ent] @16384B
//
// One kernel, 1024 blocks x 256 threads (4 waves). Wave w (global, 0..4095):
//   pair p = 2 rows, rows laid out as: [0,n_ent) entity rows -> escore;
//   [n_ent, n_ent+2D) Wq rows -> qpart[k] = c[k]*(Wq[k].Ws[:D]); row n_ent+2D
//   -> qpart[2048] = bq.Ws[:D].  Wave does pair w, plus pair w+(npairs-4096)
//   if w >= 8192-npairs (second pairs go to NON-consumer blocks).
// Publish: barrier (drains vmcnt per wave) -> flag[bid]=MAGIC.
// Consumers (bid<NSCORE): wave0 polls all 1024 flags (s_sleep(2) backoff),
// then all 256 threads reduce qpart in fixed order, gather escore, sigmoid.
// Replay-safe: stale MAGIC short-circuits onto bitwise-identical recomputed
// values (deterministic); first post-poison call sees 0xAA... and waits.
__global__ __launch_bounds__(256, 4)
void k_fused(const int* __restrict__ subject,
             const int* __restrict__ relation,
             const int* __restrict__ cand,
             const float* __restrict__ ent,
             const float* __restrict__ rel,
             const float* __restrict__ Wq,
             const float* __restrict__ bq,
             const float* __restrict__ Ws,
             const float* __restrict__ bs,
             float* __restrict__ out,
             unsigned* __restrict__ flags,
             float* __restrict__ qpart,
             float* __restrict__ escore,
             int n_ent, int n_cand, int npairs, int nrows) {
    const int bid  = blockIdx.x;
    const int tid  = threadIdx.x;
    const int wid  = tid >> 6;
    const int lane = tid & 63;
    const int w    = bid * 4 + wid;          // global wave id, 0..4095

    // Prefetch candidate (normal load; input buffer is read-only).
    int my_cand = 0;
    const int out_i = bid * 256 + tid;
    if (bid < NSCORE && out_i < n_cand) my_cand = cand[out_i];

    const int s = subject[0];
    const int r = relation[0];

    auto do_pair = [&](int pair) {
        const int row0 = pair * 2;
        const int row1 = row0 + 1;
        const bool is_ent = (row0 < n_ent);
        const float* rp0;
        const float* rp1;
        float m0 = 1.f, m1 = 1.f;
        if (is_ent) {
            rp0 = ent + (size_t)row0 * DIM;
            rp1 = rp0 + DIM;
        } else if (row0 < n_ent + 2 * DIM) {
            const int k0 = row0 - n_ent;     // even
            if (k0 < DIM) {
                m0 = ent[(size_t)s * DIM + k0];
                m1 = ent[(size_t)s * DIM + k0 + 1];
            } else {
                m0 = rel[(size_t)r * DIM + (k0 - DIM)];
                m1 = rel[(size_t)r * DIM + (k0 - DIM + 1)];
            }
            rp0 = Wq + (size_t)k0 * DIM;
            rp1 = rp0 + DIM;
        } else {                             // bias row (row1 invalid)
            rp0 = bq; rp1 = bq; m1 = 0.f;
        }
        const float* wsrc = is_ent ? (Ws + DIM) : Ws;
        float acc0 = 0.f, acc1 = 0.f;
#pragma unroll
        for (int it = 0; it < 4; ++it) {
            const int j = (it * 64 + lane) * 4;
            float4 wv = *(const float4*)(wsrc + j);
            float4 a0 = *(const float4*)(rp0 + j);
            float4 a1 = *(const float4*)(rp1 + j);
            acc0 += a0.x * wv.x + a0.y * wv.y + a0.z * wv.z + a0.w * wv.w;
            acc1 += a1.x * wv.x + a1.y * wv.y + a1.z * wv.z + a1.w * wv.w;
        }
#pragma unroll
        for (int off = 32; off; off >>= 1) {
            acc0 += __shfl_xor(acc0, off, 64);
            acc1 += __shfl_xor(acc1, off, 64);
        }
        if (lane == 0) {
            if (is_ent) {
                st_ag(&escore[row0], acc0);
                st_ag(&escore[row1], acc1);
            } else {
                const int k0 = row0 - n_ent;
                st_ag(&qpart[k0], acc0 * m0);
                if (row1 < nrows) st_ag(&qpart[k0 + 1], acc1 * m1);
            }
        }
    };

    // ---- prep: pair w for everyone; second pair for high (non-consumer) waves ----
    do_pair(w);                               // w <= 4095 < npairs always
    const int second_start = 2 * NBLK * 4 - npairs;   // 8192 - 6025 = 2167
    if (w >= second_start) do_pair(w + (npairs - NBLK * 4));

    // ---- publish (no fence; barrier drains each wave's vmcnt) ----
    __syncthreads();
    if (tid == 0) {
        asm volatile("s_waitcnt vmcnt(0)" ::: "memory");
        st_agu(&flags[bid], MAGIC);
    }
    if (bid >= NSCORE) return;

    // ---- spin: wave 0 polls all flags ----
    if (wid == 0) {
        for (;;) {
            int ok = 1;
#pragma unroll
            for (int f = 0; f < NBLK / 64; ++f)
                if (ld_agu(&flags[f * 64 + lane]) != MAGIC) ok = 0;
            if (__all(ok)) break;
            __builtin_amdgcn_s_sleep(2);
        }
    }
    __syncthreads();

    // ---- q_total: all 256 threads, fixed order (deterministic) ----
    __shared__ float swave[4];
    __shared__ float s_q;
    float v = 0.f;
    for (int i = tid; i < NQ; i += 256) v += ld_ag(&qpart[i]);
#pragma unroll
    for (int off = 32; off; off >>= 1) v += __shfl_xor(v, off, 64);
    if (lane == 0) swave[wid] = v;
    __syncthreads();
    if (tid == 0) s_q = swave[0] + swave[1] + swave[2] + swave[3] + bs[0];
    __syncthreads();

    // ---- score ----
    if (out_i < n_cand) {
        const float x = s_q + ld_ag(&escore[my_cand]);
        out[out_i] = 1.f / (1.f + expf(-x));
    }
}

extern "C" void kernel_launch(void* const* d_in, const int* in_sizes, int n_in,
                              void* d_out, int out_size, void* d_ws, size_t ws_size,
                              hipStream_t stream) {
    const int*   subject  = (const int*)d_in[0];
    const int*   relation = (const int*)d_in[1];
    const int*   cand     = (const int*)d_in[2];
    const float* ent      = (const float*)d_in[3];
    const float* rel      = (const float*)d_in[4];
    const float* Wq       = (const float*)d_in[5];
    const float* bq       = (const float*)d_in[6];
    const float* Ws       = (const float*)d_in[7];
    const float* bs       = (const float*)d_in[8];

    const int n_ent  = in_sizes[3] / DIM;             // 10000
    const int n_cand = in_sizes[2];                   // 131072

    char* ws = (char*)d_ws;
    unsigned* flags  = (unsigned*)ws;                 // 1024 u32
    float*    qpart  = (float*)(ws + 4096);           // NQ f32
    float*    escore = (float*)(ws + 16384);          // n_ent f32

    const int nrows  = n_ent + 2 * DIM + 1;           // 12049
    const int npairs = (nrows + 1) / 2;               // 6025

    k_fused<<<NBLK, 256, 0, stream>>>(subject, relation, cand, ent, rel, Wq, bq,
                                      Ws, bs, (float*)d_out, flags, qpart, escore,
                                      n_ent, n_cand, npairs, nrows);
}

// Round 7
// 17.907 us; speedup vs baseline: 1.3617x; 1.3617x over previous
//
#include <hip/hip_runtime.h>
#include <hip/hip_bf16.h>

#define DIM 1024

// Block layout for k_prep:
//   blocks [0, erow_blocks): e_score rows, 4 rows/block (1 wave each)
//   blocks [erow_blocks, erow_blocks+64): q_term partials, 32 Wq-rows each
__global__ void k_prep(const int* __restrict__ subject,
                       const int* __restrict__ relation,
                       const float* __restrict__ ent,
                       const float* __restrict__ rel,
                       const float* __restrict__ Wq,
                       const float* __restrict__ bq,
                       const float* __restrict__ Ws,
                       float* __restrict__ qpart,
                       float* __restrict__ escore,
                       int n_ent, int erow_blocks) {
    const int bid = blockIdx.x;
    const int tid = threadIdx.x;

    if (bid < erow_blocks) {
        // ---- e_score[row] = ent[row] . Ws[D:] ----
        const int wid  = tid >> 6;
        const int lane = tid & 63;
        const int row  = bid * 4 + wid;
        if (row < n_ent) {
            const float* rp = ent + (size_t)row * DIM;
            const float* wc = Ws + DIM;
            float acc = 0.f;
#pragma unroll
            for (int it = 0; it < 4; ++it) {
                const int j = (it * 64 + lane) * 4;
                float4 a = *(const float4*)(rp + j);
                float4 w = *(const float4*)(wc + j);
                acc += a.x * w.x + a.y * w.y + a.z * w.z + a.w * w.w;
            }
#pragma unroll
            for (int off = 32; off; off >>= 1) acc += __shfl_down(acc, off, 64);
            if (lane == 0) escore[row] = acc;
        }
    } else {
        // ---- q_term partial over Wq rows [b*32, b*32+32) ----
        const int b = bid - erow_blocks;           // 0..63
        const int s = subject[0];
        const int r = relation[0];
        const int j = tid * 4;                     // this thread's 4 columns
        float4 acc = make_float4(0.f, 0.f, 0.f, 0.f);
        const int k0 = b * 32;
#pragma unroll 4
        for (int kk = 0; kk < 32; ++kk) {
            const int k = k0 + kk;
            const float c = (k < DIM) ? ent[(size_t)s * DIM + k]
                                      : rel[(size_t)r * DIM + (k - DIM)];
            float4 wrow = *(const float4*)(Wq + (size_t)k * DIM + j);
            acc.x += c * wrow.x; acc.y += c * wrow.y;
            acc.z += c * wrow.z; acc.w += c * wrow.w;
        }
        float4 wt = *(const float4*)(Ws + j);      // Ws[:D] slice
        float p = acc.x * wt.x + acc.y * wt.y + acc.z * wt.z + acc.w * wt.w;
        if (b == 0) {                              // bq . Ws[:D] added once
            float4 bqv = *(const float4*)(bq + j);
            p += bqv.x * wt.x + bqv.y * wt.y + bqv.z * wt.z + bqv.w * wt.w;
        }
#pragma unroll
        for (int off = 32; off; off >>= 1) p += __shfl_down(p, off, 64);
        __shared__ float sp[4];
        const int wid  = tid >> 6;
        const int lane = tid & 63;
        if (lane == 0) sp[wid] = p;
        __syncthreads();
        if (tid == 0) qpart[b] = sp[0] + sp[1] + sp[2] + sp[3];
    }
}

__global__ void k_score(const int* __restrict__ cand,
                        const float* __restrict__ escore,
                        const float* __restrict__ qpart,
                        const float* __restrict__ bs,
                        float* __restrict__ out, int n) {
    __shared__ float s_qt;
    const int tid = threadIdx.x;
    if (tid < 64) {                                // wave 0 reduces the 64 partials
        float v = qpart[tid];
#pragma unroll
        for (int off = 32; off; off >>= 1) v += __shfl_down(v, off, 64);
        if (tid == 0) s_qt = v + bs[0];
    }
    __syncthreads();
    const int i = blockIdx.x * blockDim.x + tid;
    if (i < n) {
        const float x = s_qt + escore[cand[i]];
        out[i] = 1.f / (1.f + expf(-x));
    }
}

extern "C" void kernel_launch(void* const* d_in, const int* in_sizes, int n_in,
                              void* d_out, int out_size, void* d_ws, size_t ws_size,
                              hipStream_t stream) {
    const int*   subject  = (const int*)d_in[0];
    const int*   relation = (const int*)d_in[1];
    const int*   cand     = (const int*)d_in[2];
    const float* ent      = (const float*)d_in[3];
    const float* rel      = (const float*)d_in[4];
    const float* Wq       = (const float*)d_in[5];
    const float* bq       = (const float*)d_in[6];
    const float* Ws       = (const float*)d_in[7];
    const float* bs       = (const float*)d_in[8];

    const int n_ent  = in_sizes[3] / DIM;          // 10000
    const int n_cand = in_sizes[2];                // 131072

    float* qpart  = (float*)d_ws;                  // 64 floats
    float* escore = qpart + 64;                    // n_ent floats

    const int erow_blocks = (n_ent + 3) / 4;       // 2500
    k_prep<<<erow_blocks + 64, 256, 0, stream>>>(subject, relation, ent, rel,
                                                 Wq, bq, Ws, qpart, escore,
                                                 n_ent, erow_blocks);
    k_score<<<(n_cand + 255) / 256, 256, 0, stream>>>(cand, escore, qpart, bs,
                                                      (float*)d_out, n_cand);
}